// Round 1
// baseline (6603.202 us; speedup 1.0000x reference)
//
#include <hip/hip_runtime.h>

#define B 64
#define S 128
#define H 256
#define H2 512
#define H3 768
#define H4 1024
#define VOCAB 32000
#define T 32

// ---------------- prep: Uw2T[k][j] = Uw[j][k] + Uw[j][k+H]  (k<H, j<2H) ----------------
__global__ void prep_uw2t(const float* __restrict__ Uw, float* __restrict__ Uw2T) {
    int i = blockIdx.x * 256 + threadIdx.x;
    if (i >= H * H2) return;
    int j = i & (H2 - 1);
    int k = i >> 9;
    Uw2T[k * H2 + j] = Uw[j * H2 + k] + Uw[j * H2 + H + k];
}

// ---------------- generic-ish fp32 GEMM: C[M][N] = A[M][K] @ Wt[N][K]^T + bias[N] ------
// tiles 64x64, 256 threads, 4x4 micro-tile
__global__ __launch_bounds__(256) void gemm_bias(
    const float* __restrict__ A, const float* __restrict__ Wt,
    const float* __restrict__ bias, float* __restrict__ C,
    int M, int N, int K)
{
    __shared__ float As[64][68];
    __shared__ float Bs[64][68];
    int row0 = blockIdx.x * 64, col0 = blockIdx.y * 64;
    int tid = threadIdx.x;
    int tm = tid & 15, tn = tid >> 4;
    float acc[4][4] = {};
    for (int k0 = 0; k0 < K; k0 += 64) {
        #pragma unroll
        for (int i = 0; i < 4; i++) {
            int r = (tid >> 4) + i * 16;
            *(float4*)&As[r][(tid & 15) * 4] =
                *(const float4*)&A[(size_t)(row0 + r) * K + k0 + (tid & 15) * 4];
            *(float4*)&Bs[r][(tid & 15) * 4] =
                *(const float4*)&Wt[(size_t)(col0 + r) * K + k0 + (tid & 15) * 4];
        }
        __syncthreads();
        #pragma unroll
        for (int k = 0; k < 64; k += 4) {
            float4 a4[4], b4[4];
            #pragma unroll
            for (int i = 0; i < 4; i++) a4[i] = *(float4*)&As[tm * 4 + i][k];
            #pragma unroll
            for (int j = 0; j < 4; j++) b4[j] = *(float4*)&Bs[tn * 4 + j][k];
            #pragma unroll
            for (int i = 0; i < 4; i++)
                #pragma unroll
                for (int j = 0; j < 4; j++)
                    acc[i][j] += a4[i].x * b4[j].x + a4[i].y * b4[j].y +
                                 a4[i].z * b4[j].z + a4[i].w * b4[j].w;
        }
        __syncthreads();
    }
    #pragma unroll
    for (int i = 0; i < 4; i++)
        #pragma unroll
        for (int j = 0; j < 4; j++) {
            int r = row0 + tm * 4 + i, c = col0 + tn * 4 + j;
            C[(size_t)r * N + c] = acc[i][j] + bias[c];
        }
}

// ---------------- per-step attention (one block per batch row) -------------------------
__global__ __launch_bounds__(512) void attn_step(
    const float* __restrict__ enc, const float* __restrict__ encp,
    const float* __restrict__ Uw2T, const float* __restrict__ Ub,
    const float* __restrict__ Vw, const float* __restrict__ Vb,
    const float* __restrict__ hsrc,                 // dir0 slice [B][H]
    const unsigned long long* __restrict__ keys,    // argmax keys from prev step
    const float* __restrict__ emb,
    float* __restrict__ xin)                        // [B][H3]
{
    __shared__ float hf[H];
    __shared__ float qp[H2];
    __shared__ float sc[S];
    __shared__ float rmax, rsum;
    int b = blockIdx.x, tid = threadIdx.x;

    if (tid < H) hf[tid] = hsrc[b * H + tid];
    __syncthreads();

    // qp[j] = Ub[j] + sum_k hf[k] * Uw2T[k][j]   (coalesced over j)
    {
        float s = Ub[tid];
        for (int k = 0; k < H; k++) s += hf[k] * Uw2T[k * H2 + tid];
        qp[tid] = s;
    }
    __syncthreads();

    // scores: 4 lanes per s, interleaved float4 chunks for coalescing
    {
        int si = tid >> 2, p = tid & 3;
        const float* ep = encp + ((size_t)(b * S + si)) * H2;
        float a = 0.f;
        for (int m = 0; m < 32; m++) {
            int q = (m * 4 + p) * 4;
            float4 e4 = *(const float4*)(ep + q);
            float4 v4 = *(const float4*)(Vw + q);
            float4 q4 = *(const float4*)(qp + q);
            a += v4.x * tanhf(q4.x + e4.x);
            a += v4.y * tanhf(q4.y + e4.y);
            a += v4.z * tanhf(q4.z + e4.z);
            a += v4.w * tanhf(q4.w + e4.w);
        }
        a += __shfl_xor(a, 1);
        a += __shfl_xor(a, 2);
        if (p == 0) sc[si] = a + Vb[0];
    }
    __syncthreads();

    // softmax over S=128
    if (tid < 64) {
        float m = fmaxf(sc[tid], sc[tid + 64]);
        #pragma unroll
        for (int o = 32; o; o >>= 1) m = fmaxf(m, __shfl_xor(m, o));
        if (tid == 0) rmax = m;
    }
    __syncthreads();
    if (tid < S) sc[tid] = expf(sc[tid] - rmax);
    __syncthreads();
    if (tid < 64) {
        float s = sc[tid] + sc[tid + 64];
        #pragma unroll
        for (int o = 32; o; o >>= 1) s += __shfl_xor(s, o);
        if (tid == 0) rsum = s;
    }
    __syncthreads();
    if (tid < S) sc[tid] = sc[tid] / rsum;
    __syncthreads();

    // ctx[d] = sum_s w[s] * enc[b][s][d]  -> xin[b][0:512]
    {
        float a = 0.f;
        const float* eb = enc + (size_t)b * S * H2 + tid;
        for (int s2 = 0; s2 < S; s2++) a += sc[s2] * eb[(size_t)s2 * H2];
        xin[b * H3 + tid] = a;
    }
    // emb feedback -> xin[b][512:768]
    if (tid < H) {
        int idx = (int)(~(unsigned)keys[b]);
        xin[b * H3 + H2 + tid] = emb[(size_t)idx * H + tid];
    }
}

// ---------------- per-step LSTM (both dirs, gates + cell fused) ------------------------
// grid: 128 blocks = dir(2) x jgroup(64, 4 hidden units each); 256 thr = j4(4) x b(64)
__global__ __launch_bounds__(256) void lstm_step(
    const float* __restrict__ xin,
    const float* __restrict__ hsrc, const float* __restrict__ csrc,  // [2][B][H]
    const float* __restrict__ Wih_f, const float* __restrict__ Whh_f, const float* __restrict__ bf,
    const float* __restrict__ Wih_b, const float* __restrict__ Whh_b, const float* __restrict__ bb,
    float* __restrict__ hdst, float* __restrict__ cdst,
    float* __restrict__ outb,                       // [B][2H]
    unsigned long long* __restrict__ keys,
    int is_last, float* __restrict__ out_tail)      // d_out + B*T*V
{
    __shared__ float xs[64][68];
    __shared__ float Ws[16][68];
    int blk = blockIdx.x;
    int dir = blk >> 6;
    int jg = blk & 63;
    int tid = threadIdx.x;
    int b = tid & 63, j4 = tid >> 6;
    const float* Wih = dir ? Wih_b : Wih_f;
    const float* Whh = dir ? Whh_b : Whh_f;
    const float* bias = dir ? bb : bf;
    int n = jg * 4 + j4;                  // hidden index 0..255
    float acc[4];
    #pragma unroll
    for (int g = 0; g < 4; g++) acc[g] = bias[g * 256 + n];

    // xin @ Wih^T
    for (int k0 = 0; k0 < H3; k0 += 64) {
        #pragma unroll
        for (int i = 0; i < 4; i++) {
            int r = (tid >> 4) + i * 16;
            *(float4*)&xs[r][(tid & 15) * 4] =
                *(const float4*)&xin[r * H3 + k0 + (tid & 15) * 4];
        }
        {
            int r = tid >> 4, c = tid & 15;
            int grow = (r & 3) * 256 + jg * 4 + (r >> 2);
            *(float4*)&Ws[r][c * 4] = *(const float4*)&Wih[(size_t)grow * H3 + k0 + c * 4];
        }
        __syncthreads();
        #pragma unroll
        for (int k = 0; k < 64; k += 4) {
            float4 x4 = *(float4*)&xs[b][k];
            #pragma unroll
            for (int g = 0; g < 4; g++) {
                float4 w4 = *(float4*)&Ws[j4 * 4 + g][k];
                acc[g] += x4.x * w4.x + x4.y * w4.y + x4.z * w4.z + x4.w * w4.w;
            }
        }
        __syncthreads();
    }
    // h @ Whh^T
    for (int k0 = 0; k0 < H; k0 += 64) {
        #pragma unroll
        for (int i = 0; i < 4; i++) {
            int r = (tid >> 4) + i * 16;
            *(float4*)&xs[r][(tid & 15) * 4] =
                *(const float4*)&hsrc[dir * B * H + r * H + k0 + (tid & 15) * 4];
        }
        {
            int r = tid >> 4, c = tid & 15;
            int grow = (r & 3) * 256 + jg * 4 + (r >> 2);
            *(float4*)&Ws[r][c * 4] = *(const float4*)&Whh[(size_t)grow * H + k0 + c * 4];
        }
        __syncthreads();
        #pragma unroll
        for (int k = 0; k < 64; k += 4) {
            float4 x4 = *(float4*)&xs[b][k];
            #pragma unroll
            for (int g = 0; g < 4; g++) {
                float4 w4 = *(float4*)&Ws[j4 * 4 + g][k];
                acc[g] += x4.x * w4.x + x4.y * w4.y + x4.z * w4.z + x4.w * w4.w;
            }
        }
        __syncthreads();
    }

    float iv = 1.f / (1.f + expf(-acc[0]));
    float fv = 1.f / (1.f + expf(-acc[1]));
    float gv = tanhf(acc[2]);
    float ov = 1.f / (1.f + expf(-acc[3]));
    float cold = csrc[dir * B * H + b * H + n];
    float c2 = fv * cold + iv * gv;
    float h2 = ov * tanhf(c2);
    hdst[dir * B * H + b * H + n] = h2;
    cdst[dir * B * H + b * H + n] = c2;
    outb[b * H2 + dir * H + n] = h2;
    if (is_last) {
        out_tail[dir * B * H + b * H + n] = h2;                 // hT
        out_tail[2 * B * H + dir * B * H + b * H + n] = c2;     // cT
    }
    if (blk == 0 && tid < 64) keys[tid] = 0ULL;   // reset argmax keys for this step
}

// ---------------- per-step vocab projection + argmax -----------------------------------
// grid: 500 blocks (64-vocab tiles); C tile 64b x 64v
__global__ __launch_bounds__(256) void proj_step(
    const float* __restrict__ outb, const float* __restrict__ Fw,
    const float* __restrict__ Fb, float* __restrict__ ys,
    unsigned long long* __restrict__ keys, int t)
{
    __shared__ float As[64][68];
    __shared__ float Bs[64][68];
    __shared__ unsigned long long red[64][16];
    int col0 = blockIdx.x * 64;
    int tid = threadIdx.x;
    int tm = tid & 15, tn = tid >> 4;
    float acc[4][4] = {};
    for (int k0 = 0; k0 < H2; k0 += 64) {
        #pragma unroll
        for (int i = 0; i < 4; i++) {
            int r = (tid >> 4) + i * 16;
            *(float4*)&As[r][(tid & 15) * 4] =
                *(const float4*)&outb[r * H2 + k0 + (tid & 15) * 4];
            *(float4*)&Bs[r][(tid & 15) * 4] =
                *(const float4*)&Fw[(size_t)(col0 + r) * H2 + k0 + (tid & 15) * 4];
        }
        __syncthreads();
        #pragma unroll
        for (int k = 0; k < 64; k += 4) {
            float4 a4[4], b4[4];
            #pragma unroll
            for (int i = 0; i < 4; i++) a4[i] = *(float4*)&As[tm * 4 + i][k];
            #pragma unroll
            for (int j = 0; j < 4; j++) b4[j] = *(float4*)&Bs[tn * 4 + j][k];
            #pragma unroll
            for (int i = 0; i < 4; i++)
                #pragma unroll
                for (int j = 0; j < 4; j++)
                    acc[i][j] += a4[i].x * b4[j].x + a4[i].y * b4[j].y +
                                 a4[i].z * b4[j].z + a4[i].w * b4[j].w;
        }
        __syncthreads();
    }
    #pragma unroll
    for (int i = 0; i < 4; i++) {
        int b = tm * 4 + i;
        unsigned long long best = 0ULL;
        #pragma unroll
        for (int j = 0; j < 4; j++) {
            int v = col0 + tn * 4 + j;
            float y = acc[i][j] + Fb[v];
            ys[(size_t)b * (T * (size_t)VOCAB) + (size_t)t * VOCAB + v] = y;
            unsigned u = __float_as_uint(y);
            u = (u & 0x80000000u) ? ~u : (u | 0x80000000u);
            unsigned long long key = ((unsigned long long)u << 32) | (unsigned)(~v);
            if (key > best) best = key;
        }
        red[b][tn] = best;
    }
    __syncthreads();
    if (tid < 64) {
        unsigned long long best = red[tid][0];
        #pragma unroll
        for (int j = 1; j < 16; j++) { unsigned long long k2 = red[tid][j]; if (k2 > best) best = k2; }
        atomicMax(&keys[tid], best);
    }
}

// ---------------- host launch ----------------------------------------------------------
extern "C" void kernel_launch(void* const* d_in, const int* in_sizes, int n_in,
                              void* d_out, int out_size, void* d_ws, size_t ws_size,
                              hipStream_t stream) {
    const float* enc   = (const float*)d_in[0];
    const float* h0    = (const float*)d_in[1];
    const float* c0    = (const float*)d_in[2];
    const float* Uw    = (const float*)d_in[3];
    const float* Ub    = (const float*)d_in[4];
    const float* Ww    = (const float*)d_in[5];
    const float* Wb    = (const float*)d_in[6];
    const float* Vw    = (const float*)d_in[7];
    const float* Vb    = (const float*)d_in[8];
    const float* Wih_f = (const float*)d_in[9];
    const float* Whh_f = (const float*)d_in[10];
    const float* b_f   = (const float*)d_in[11];
    const float* Wih_b = (const float*)d_in[12];
    const float* Whh_b = (const float*)d_in[13];
    const float* b_b   = (const float*)d_in[14];
    const float* Fw    = (const float*)d_in[15];
    const float* Fb    = (const float*)d_in[16];
    const float* emb   = (const float*)d_in[17];
    float* out = (float*)d_out;

    float* ws = (float*)d_ws;
    float* encp = ws;                                   // B*S*H2      = 4,194,304
    float* Uw2T = encp + (size_t)B * S * H2;            // H*H2        =   131,072
    float* xin  = Uw2T + (size_t)H * H2;                // B*H3        =    49,152
    float* hA   = xin + (size_t)B * H3;                 // 2*B*H       =    32,768
    float* hB   = hA + 2 * B * H;                       // 2*B*H
    float* cA   = hB + 2 * B * H;                       // 2*B*H
    float* cB   = cA + 2 * B * H;                       // 2*B*H
    float* outb = cB + 2 * B * H;                       // B*H2        =    32,768
    unsigned long long* keys = (unsigned long long*)(outb + (size_t)B * H2);

    // keys = all-ones -> decodes to token 0 at t=0
    hipMemsetAsync(keys, 0xFF, B * sizeof(unsigned long long), stream);

    prep_uw2t<<<(H * H2 + 255) / 256, 256, 0, stream>>>(Uw, Uw2T);
    // enc_proj = enc @ Ww^T + Wb : M=B*S=8192, N=512, K=512
    gemm_bias<<<dim3(128, 8), 256, 0, stream>>>(enc, Ww, Wb, encp, B * S, H2, H2);

    for (int t = 0; t < T; t++) {
        const float* hsrc = (t == 0) ? h0 : ((t & 1) ? hA : hB);
        const float* csrc = (t == 0) ? c0 : ((t & 1) ? cA : cB);
        float* hdst = (t & 1) ? hB : hA;
        float* cdst = (t & 1) ? cB : cA;

        attn_step<<<B, 512, 0, stream>>>(enc, encp, Uw2T, Ub, Vw, Vb,
                                         hsrc /* dir0 slice first */, keys, emb, xin);
        lstm_step<<<128, 256, 0, stream>>>(xin, hsrc, csrc,
                                           Wih_f, Whh_f, b_f, Wih_b, Whh_b, b_b,
                                           hdst, cdst, outb, keys,
                                           (t == T - 1) ? 1 : 0,
                                           out + (size_t)B * T * VOCAB);
        proj_step<<<VOCAB / 64, 256, 0, stream>>>(outb, Fw, Fb, out, keys, t);
    }
}

// Round 3
// 5764.867 us; speedup vs baseline: 1.1454x; 1.1454x over previous
//
#include <hip/hip_runtime.h>

#define B 64
#define S 128
#define H 256
#define H2 512
#define H3 768
#define VOCAB 32000
#define T 32

typedef __attribute__((ext_vector_type(8))) short bf16x8;
typedef __attribute__((ext_vector_type(4))) float f32x4;
typedef __attribute__((ext_vector_type(4))) unsigned short ushort4v;

// ---- bf16 split helpers (RNE, bit-level, no API dependence) ---------------------------
__device__ __forceinline__ unsigned short f2bf(float x) {
    unsigned u = __float_as_uint(x);
    return (unsigned short)((u + 0x7FFFu + ((u >> 16) & 1u)) >> 16);
}
__device__ __forceinline__ float bf2f(unsigned short h) {
    return __uint_as_float((unsigned)h << 16);
}
__device__ __forceinline__ void split2(float x, unsigned short& h, unsigned short& l) {
    h = f2bf(x);
    l = f2bf(x - bf2f(h));
}

// ---- prep: Uw2T[k][j] = Uw[j][k] + Uw[j][k+H] -----------------------------------------
__global__ void prep_uw2t(const float* __restrict__ Uw, float* __restrict__ Uw2T) {
    int i = blockIdx.x * 256 + threadIdx.x;
    if (i >= H * H2) return;
    int j = i & (H2 - 1);
    int k = i >> 9;
    Uw2T[k * H2 + j] = Uw[j * H2 + k] + Uw[j * H2 + H + k];
}

// ---- prep: split fp32 array into bf16 hi/lo -------------------------------------------
__global__ __launch_bounds__(256) void split_bf16(
    const float* __restrict__ in, unsigned short* __restrict__ hi,
    unsigned short* __restrict__ lo, int n)
{
    int stride = gridDim.x * 256 * 4;
    for (int i = (blockIdx.x * 256 + threadIdx.x) * 4; i < n; i += stride) {
        float4 v = *(const float4*)&in[i];
        ushort4v h4, l4;
        unsigned short h, l;
        split2(v.x, h, l); h4[0] = h; l4[0] = l;
        split2(v.y, h, l); h4[1] = h; l4[1] = l;
        split2(v.z, h, l); h4[2] = h; l4[2] = l;
        split2(v.w, h, l); h4[3] = h; l4[3] = l;
        *(ushort4v*)&hi[i] = h4;
        *(ushort4v*)&lo[i] = l4;
    }
}

// ---- bf16x3 MFMA GEMM: C[m][n] = A[m][:]·Wt[n][:] + bias[n], K=512 --------------------
// 1 wave per block, 64x64 output tile. grid = (N/64, M/64).
__global__ __launch_bounds__(64) void gemm_bf16x3(
    const unsigned short* __restrict__ Ahi, const unsigned short* __restrict__ Alo,
    const unsigned short* __restrict__ Bhi, const unsigned short* __restrict__ Blo,
    const float* __restrict__ bias, float* __restrict__ C, int Ncols)
{
    const int K = H2;
    int l = threadIdx.x;
    int n0 = blockIdx.x * 64, m0 = blockIdx.y * 64;
    int lr = l & 15, lg = l >> 4;
    f32x4 acc[4][4] = {};
    size_t aoff = (size_t)(m0 + lr) * K + lg * 8;
    size_t boff = (size_t)(n0 + lr) * K + lg * 8;
    #pragma unroll 2
    for (int ks = 0; ks < 16; ks++) {
        bf16x8 ah[4], al[4], bh[4], bl[4];
        #pragma unroll
        for (int mt = 0; mt < 4; mt++) {
            size_t o = aoff + (size_t)mt * 16 * K + ks * 32;
            ah[mt] = *(const bf16x8*)(Ahi + o);
            al[mt] = *(const bf16x8*)(Alo + o);
        }
        #pragma unroll
        for (int nt = 0; nt < 4; nt++) {
            size_t o = boff + (size_t)nt * 16 * K + ks * 32;
            bh[nt] = *(const bf16x8*)(Bhi + o);
            bl[nt] = *(const bf16x8*)(Blo + o);
        }
        #pragma unroll
        for (int mt = 0; mt < 4; mt++)
            #pragma unroll
            for (int nt = 0; nt < 4; nt++) {
                acc[mt][nt] = __builtin_amdgcn_mfma_f32_16x16x32_bf16(ah[mt], bh[nt], acc[mt][nt], 0, 0, 0);
                acc[mt][nt] = __builtin_amdgcn_mfma_f32_16x16x32_bf16(ah[mt], bl[nt], acc[mt][nt], 0, 0, 0);
                acc[mt][nt] = __builtin_amdgcn_mfma_f32_16x16x32_bf16(al[mt], bh[nt], acc[mt][nt], 0, 0, 0);
            }
    }
    #pragma unroll
    for (int mt = 0; mt < 4; mt++)
        #pragma unroll
        for (int r = 0; r < 4; r++) {
            int m = m0 + mt * 16 + lg * 4 + r;
            #pragma unroll
            for (int nt = 0; nt < 4; nt++) {
                int n = n0 + nt * 16 + lr;
                C[(size_t)m * Ncols + n] = acc[mt][nt][r] + bias[n];
            }
        }
}

// ---- per-step vocab projection: bf16x3 MFMA + bias + ys store + argmax ----------------
// 1 wave per block, 64 rows x 64 vocab cols. grid = 500.
__global__ __launch_bounds__(64) void proj_mfma(
    const unsigned short* __restrict__ Ahi, const unsigned short* __restrict__ Alo,  // [64][512]
    const unsigned short* __restrict__ Bhi, const unsigned short* __restrict__ Blo,  // [V][512]
    const float* __restrict__ Fb, float* __restrict__ ys,
    unsigned long long* __restrict__ keys, int t)
{
    const int K = H2;
    int l = threadIdx.x;
    int n0 = blockIdx.x * 64;
    int lr = l & 15, lg = l >> 4;
    f32x4 acc[4][4] = {};
    size_t aoff = (size_t)lr * K + lg * 8;
    size_t boff = (size_t)(n0 + lr) * K + lg * 8;
    #pragma unroll 2
    for (int ks = 0; ks < 16; ks++) {
        bf16x8 ah[4], al[4], bh[4], bl[4];
        #pragma unroll
        for (int mt = 0; mt < 4; mt++) {
            size_t o = aoff + (size_t)mt * 16 * K + ks * 32;
            ah[mt] = *(const bf16x8*)(Ahi + o);
            al[mt] = *(const bf16x8*)(Alo + o);
        }
        #pragma unroll
        for (int nt = 0; nt < 4; nt++) {
            size_t o = boff + (size_t)nt * 16 * K + ks * 32;
            bh[nt] = *(const bf16x8*)(Bhi + o);
            bl[nt] = *(const bf16x8*)(Blo + o);
        }
        #pragma unroll
        for (int mt = 0; mt < 4; mt++)
            #pragma unroll
            for (int nt = 0; nt < 4; nt++) {
                acc[mt][nt] = __builtin_amdgcn_mfma_f32_16x16x32_bf16(ah[mt], bh[nt], acc[mt][nt], 0, 0, 0);
                acc[mt][nt] = __builtin_amdgcn_mfma_f32_16x16x32_bf16(ah[mt], bl[nt], acc[mt][nt], 0, 0, 0);
                acc[mt][nt] = __builtin_amdgcn_mfma_f32_16x16x32_bf16(al[mt], bh[nt], acc[mt][nt], 0, 0, 0);
            }
    }
    #pragma unroll
    for (int mt = 0; mt < 4; mt++)
        #pragma unroll
        for (int r = 0; r < 4; r++) {
            int m = mt * 16 + lg * 4 + r;   // batch row
            unsigned long long best = 0ULL;
            #pragma unroll
            for (int nt = 0; nt < 4; nt++) {
                int n = n0 + nt * 16 + lr;
                float y = acc[mt][nt][r] + Fb[n];
                ys[(size_t)m * (T * (size_t)VOCAB) + (size_t)t * VOCAB + n] = y;
                unsigned u = __float_as_uint(y);
                u = (u & 0x80000000u) ? ~u : (u | 0x80000000u);
                unsigned long long key = ((unsigned long long)u << 32) | (unsigned)(~n);
                if (key > best) best = key;
            }
            // reduce across the 16 lanes (lr) that share row m
            #pragma unroll
            for (int o = 1; o < 16; o <<= 1) {
                unsigned long long other = __shfl_xor(best, o);
                if (other > best) best = other;
            }
            if (lr == 0) atomicMax(&keys[m], best);
        }
}

// ---- per-step attention (one block per batch row) -------------------------------------
__global__ __launch_bounds__(512) void attn_step(
    const float* __restrict__ enc, const float* __restrict__ encp,
    const float* __restrict__ Uw2T, const float* __restrict__ Ub,
    const float* __restrict__ Vw, const float* __restrict__ Vb,
    const float* __restrict__ hsrc,
    const unsigned long long* __restrict__ keys,
    const float* __restrict__ emb,
    float* __restrict__ xin)
{
    __shared__ float hf[H];
    __shared__ float qp[H2];
    __shared__ float sc[S];
    __shared__ float rmax, rsum;
    int b = blockIdx.x, tid = threadIdx.x;

    if (tid < H) hf[tid] = hsrc[b * H + tid];
    __syncthreads();

    {
        float s = Ub[tid];
        for (int k = 0; k < H; k++) s += hf[k] * Uw2T[k * H2 + tid];
        qp[tid] = s;
    }
    __syncthreads();

    {
        int si = tid >> 2, p = tid & 3;
        const float* ep = encp + ((size_t)(b * S + si)) * H2;
        float a = 0.f;
        for (int m = 0; m < 32; m++) {
            int q = (m * 4 + p) * 4;
            float4 e4 = *(const float4*)(ep + q);
            float4 v4 = *(const float4*)(Vw + q);
            float4 q4 = *(const float4*)(qp + q);
            a += v4.x * tanhf(q4.x + e4.x);
            a += v4.y * tanhf(q4.y + e4.y);
            a += v4.z * tanhf(q4.z + e4.z);
            a += v4.w * tanhf(q4.w + e4.w);
        }
        a += __shfl_xor(a, 1);
        a += __shfl_xor(a, 2);
        if (p == 0) sc[si] = a + Vb[0];
    }
    __syncthreads();

    if (tid < 64) {
        float m = fmaxf(sc[tid], sc[tid + 64]);
        #pragma unroll
        for (int o = 32; o; o >>= 1) m = fmaxf(m, __shfl_xor(m, o));
        if (tid == 0) rmax = m;
    }
    __syncthreads();
    if (tid < S) sc[tid] = expf(sc[tid] - rmax);
    __syncthreads();
    if (tid < 64) {
        float s = sc[tid] + sc[tid + 64];
        #pragma unroll
        for (int o = 32; o; o >>= 1) s += __shfl_xor(s, o);
        if (tid == 0) rsum = s;
    }
    __syncthreads();
    if (tid < S) sc[tid] = sc[tid] / rsum;
    __syncthreads();

    {
        float a = 0.f;
        const float* eb = enc + (size_t)b * S * H2 + tid;
        for (int s2 = 0; s2 < S; s2++) a += sc[s2] * eb[(size_t)s2 * H2];
        xin[b * H3 + tid] = a;
    }
    if (tid < H) {
        int idx = (int)(~(unsigned)keys[b]);
        xin[b * H3 + H2 + tid] = emb[(size_t)idx * H + tid];
    }
}

// ---- per-step LSTM (both dirs fused); transposed LDS (bank-conflict-free reads) -------
__global__ __launch_bounds__(256) void lstm_step(
    const float* __restrict__ xin,
    const float* __restrict__ hsrc, const float* __restrict__ csrc,
    const float* __restrict__ Wih_f, const float* __restrict__ Whh_f, const float* __restrict__ bf,
    const float* __restrict__ Wih_b, const float* __restrict__ Whh_b, const float* __restrict__ bb,
    float* __restrict__ hdst, float* __restrict__ cdst,
    unsigned short* __restrict__ outb_hi, unsigned short* __restrict__ outb_lo,
    unsigned long long* __restrict__ keys,
    int is_last, float* __restrict__ out_tail)
{
    __shared__ float xs[64][65];   // transposed: xs[k][row]
    __shared__ float Ws[16][68];
    int blk = blockIdx.x;
    int dir = blk >> 6;
    int jg = blk & 63;
    int tid = threadIdx.x;
    int b = tid & 63, j4 = tid >> 6;
    const float* Wih = dir ? Wih_b : Wih_f;
    const float* Whh = dir ? Whh_b : Whh_f;
    const float* bias = dir ? bb : bf;
    int n = jg * 4 + j4;
    float acc[4];
    #pragma unroll
    for (int g = 0; g < 4; g++) acc[g] = bias[g * 256 + n];

    for (int k0 = 0; k0 < H3; k0 += 64) {
        #pragma unroll
        for (int i = 0; i < 4; i++) {
            int r = (tid >> 4) + i * 16;
            int c = tid & 15;
            float4 v = *(const float4*)&xin[r * H3 + k0 + c * 4];
            xs[c * 4 + 0][r] = v.x; xs[c * 4 + 1][r] = v.y;
            xs[c * 4 + 2][r] = v.z; xs[c * 4 + 3][r] = v.w;
        }
        {
            int r = tid >> 4, c = tid & 15;
            int grow = (r & 3) * 256 + jg * 4 + (r >> 2);
            *(float4*)&Ws[r][c * 4] = *(const float4*)&Wih[(size_t)grow * H3 + k0 + c * 4];
        }
        __syncthreads();
        #pragma unroll
        for (int k = 0; k < 64; k += 4) {
            float x0 = xs[k][b], x1 = xs[k + 1][b], x2 = xs[k + 2][b], x3 = xs[k + 3][b];
            #pragma unroll
            for (int g = 0; g < 4; g++) {
                float4 w4 = *(float4*)&Ws[j4 * 4 + g][k];
                acc[g] += x0 * w4.x + x1 * w4.y + x2 * w4.z + x3 * w4.w;
            }
        }
        __syncthreads();
    }
    for (int k0 = 0; k0 < H; k0 += 64) {
        #pragma unroll
        for (int i = 0; i < 4; i++) {
            int r = (tid >> 4) + i * 16;
            int c = tid & 15;
            float4 v = *(const float4*)&hsrc[dir * B * H + r * H + k0 + c * 4];
            xs[c * 4 + 0][r] = v.x; xs[c * 4 + 1][r] = v.y;
            xs[c * 4 + 2][r] = v.z; xs[c * 4 + 3][r] = v.w;
        }
        {
            int r = tid >> 4, c = tid & 15;
            int grow = (r & 3) * 256 + jg * 4 + (r >> 2);
            *(float4*)&Ws[r][c * 4] = *(const float4*)&Whh[(size_t)grow * H + k0 + c * 4];
        }
        __syncthreads();
        #pragma unroll
        for (int k = 0; k < 64; k += 4) {
            float x0 = xs[k][b], x1 = xs[k + 1][b], x2 = xs[k + 2][b], x3 = xs[k + 3][b];
            #pragma unroll
            for (int g = 0; g < 4; g++) {
                float4 w4 = *(float4*)&Ws[j4 * 4 + g][k];
                acc[g] += x0 * w4.x + x1 * w4.y + x2 * w4.z + x3 * w4.w;
            }
        }
        __syncthreads();
    }

    float iv = 1.f / (1.f + expf(-acc[0]));
    float fv = 1.f / (1.f + expf(-acc[1]));
    float gv = tanhf(acc[2]);
    float ov = 1.f / (1.f + expf(-acc[3]));
    float cold = csrc[dir * B * H + b * H + n];
    float c2 = fv * cold + iv * gv;
    float h2 = ov * tanhf(c2);
    hdst[dir * B * H + b * H + n] = h2;
    cdst[dir * B * H + b * H + n] = c2;
    unsigned short hh, hl;
    split2(h2, hh, hl);
    outb_hi[b * H2 + dir * H + n] = hh;
    outb_lo[b * H2 + dir * H + n] = hl;
    if (is_last) {
        out_tail[dir * B * H + b * H + n] = h2;
        out_tail[2 * B * H + dir * B * H + b * H + n] = c2;
    }
    if (blk == 0 && tid < 64) keys[tid] = 0ULL;
}

// ---- host launch ----------------------------------------------------------------------
static inline size_t align256(size_t x) { return (x + 255) & ~(size_t)255; }

extern "C" void kernel_launch(void* const* d_in, const int* in_sizes, int n_in,
                              void* d_out, int out_size, void* d_ws, size_t ws_size,
                              hipStream_t stream) {
    const float* enc   = (const float*)d_in[0];
    const float* h0    = (const float*)d_in[1];
    const float* c0    = (const float*)d_in[2];
    const float* Uw    = (const float*)d_in[3];
    const float* Ub    = (const float*)d_in[4];
    const float* Ww    = (const float*)d_in[5];
    const float* Wb    = (const float*)d_in[6];
    const float* Vw    = (const float*)d_in[7];
    const float* Vb    = (const float*)d_in[8];
    const float* Wih_f = (const float*)d_in[9];
    const float* Whh_f = (const float*)d_in[10];
    const float* b_f   = (const float*)d_in[11];
    const float* Wih_b = (const float*)d_in[12];
    const float* Whh_b = (const float*)d_in[13];
    const float* b_b   = (const float*)d_in[14];
    const float* Fw    = (const float*)d_in[15];
    const float* Fb    = (const float*)d_in[16];
    const float* emb   = (const float*)d_in[17];
    float* out = (float*)d_out;

    char* p = (char*)d_ws;
    size_t off = 0;
    #define ALLOC(name, bytes) char* name##_p = p + off; off = align256(off + (bytes))
    ALLOC(encp, (size_t)B * S * H2 * 4);
    ALLOC(uw2t, (size_t)H * H2 * 4);
    ALLOC(xin,  (size_t)B * H3 * 4);
    ALLOC(hA,   (size_t)2 * B * H * 4);
    ALLOC(hB,   (size_t)2 * B * H * 4);
    ALLOC(cA,   (size_t)2 * B * H * 4);
    ALLOC(cB,   (size_t)2 * B * H * 4);
    ALLOC(obh,  (size_t)B * H2 * 2);
    ALLOC(obl,  (size_t)B * H2 * 2);
    ALLOC(fwh,  (size_t)VOCAB * H2 * 2);
    ALLOC(fwl,  (size_t)VOCAB * H2 * 2);
    ALLOC(ench, (size_t)B * S * H2 * 2);
    ALLOC(encl, (size_t)B * S * H2 * 2);
    ALLOC(wwh,  (size_t)H2 * H2 * 2);
    ALLOC(wwl,  (size_t)H2 * H2 * 2);
    ALLOC(keys, (size_t)B * 8);
    #undef ALLOC

    float* encp_f = (float*)encp_p;
    float* Uw2T   = (float*)uw2t_p;
    float* xin_f  = (float*)xin_p;
    float* hA_f = (float*)hA_p; float* hB_f = (float*)hB_p;
    float* cA_f = (float*)cA_p; float* cB_f = (float*)cB_p;
    unsigned short* obh_u = (unsigned short*)obh_p;
    unsigned short* obl_u = (unsigned short*)obl_p;
    unsigned short* fwh_u = (unsigned short*)fwh_p;
    unsigned short* fwl_u = (unsigned short*)fwl_p;
    unsigned short* ench_u = (unsigned short*)ench_p;
    unsigned short* encl_u = (unsigned short*)encl_p;
    unsigned short* wwh_u = (unsigned short*)wwh_p;
    unsigned short* wwl_u = (unsigned short*)wwl_p;
    unsigned long long* keys_u = (unsigned long long*)keys_p;

    (void)hipMemsetAsync(keys_u, 0xFF, B * sizeof(unsigned long long), stream);

    prep_uw2t<<<(H * H2 + 255) / 256, 256, 0, stream>>>(Uw, Uw2T);
    split_bf16<<<2048, 256, 0, stream>>>(Fw, fwh_u, fwl_u, VOCAB * H2);
    split_bf16<<<1024, 256, 0, stream>>>(enc, ench_u, encl_u, B * S * H2);
    split_bf16<<<256, 256, 0, stream>>>(Ww, wwh_u, wwl_u, H2 * H2);
    // enc_proj = enc @ Ww^T + Wb  (M = B*S = 8192, N = 512)
    gemm_bf16x3<<<dim3(8, 128), 64, 0, stream>>>(ench_u, encl_u, wwh_u, wwl_u, Wb, encp_f, H2);

    for (int t = 0; t < T; t++) {
        const float* hsrc = (t == 0) ? h0 : ((t & 1) ? hA_f : hB_f);
        const float* csrc = (t == 0) ? c0 : ((t & 1) ? cA_f : cB_f);
        float* hdst = (t & 1) ? hB_f : hA_f;
        float* cdst = (t & 1) ? cB_f : cA_f;

        attn_step<<<B, 512, 0, stream>>>(enc, encp_f, Uw2T, Ub, Vw, Vb,
                                         hsrc, keys_u, emb, xin_f);
        lstm_step<<<128, 256, 0, stream>>>(xin_f, hsrc, csrc,
                                           Wih_f, Whh_f, b_f, Wih_b, Whh_b, b_b,
                                           hdst, cdst, obh_u, obl_u, keys_u,
                                           (t == T - 1) ? 1 : 0,
                                           out + (size_t)B * T * VOCAB);
        proj_mfma<<<VOCAB / 64, 64, 0, stream>>>(obh_u, obl_u, fwh_u, fwl_u,
                                                 Fb, out, keys_u, t);
    }
}

// Round 5
// 4397.491 us; speedup vs baseline: 1.5016x; 1.3109x over previous
//
#include <hip/hip_runtime.h>

#define B 64
#define S 128
#define H 256
#define H2 512
#define H3 768
#define VOCAB 32000
#define T 32
#define PW 2048   // partials row width (500 blocks * 4 waves = 2000 used)

typedef __attribute__((ext_vector_type(8))) short bf16x8;
typedef __attribute__((ext_vector_type(4))) float f32x4;
typedef __attribute__((ext_vector_type(4))) unsigned short ushort4v;

// ---- bf16 split helpers ---------------------------------------------------------------
__device__ __forceinline__ unsigned short f2bf(float x) {
    unsigned u = __float_as_uint(x);
    return (unsigned short)((u + 0x7FFFu + ((u >> 16) & 1u)) >> 16);
}
__device__ __forceinline__ float bf2f(unsigned short h) {
    return __uint_as_float((unsigned)h << 16);
}
__device__ __forceinline__ void split2(float x, unsigned short& h, unsigned short& l) {
    h = f2bf(x);
    l = f2bf(x - bf2f(h));
}

// ---- prep: Uw2T[k][j] = Uw[j][k] + Uw[j][k+H] -----------------------------------------
__global__ void prep_uw2t(const float* __restrict__ Uw, float* __restrict__ Uw2T) {
    int i = blockIdx.x * 256 + threadIdx.x;
    if (i >= H * H2) return;
    int j = i & (H2 - 1);
    int k = i >> 9;
    Uw2T[k * H2 + j] = Uw[j * H2 + k] + Uw[j * H2 + H + k];
}

// ---- prep: split fp32 array into bf16 hi/lo -------------------------------------------
__global__ __launch_bounds__(256) void split_bf16(
    const float* __restrict__ in, unsigned short* __restrict__ hi,
    unsigned short* __restrict__ lo, int n)
{
    int stride = gridDim.x * 256 * 4;
    for (int i = (blockIdx.x * 256 + threadIdx.x) * 4; i < n; i += stride) {
        float4 v = *(const float4*)&in[i];
        ushort4v h4, l4;
        unsigned short h, l;
        split2(v.x, h, l); h4[0] = h; l4[0] = l;
        split2(v.y, h, l); h4[1] = h; l4[1] = l;
        split2(v.z, h, l); h4[2] = h; l4[2] = l;
        split2(v.w, h, l); h4[3] = h; l4[3] = l;
        *(ushort4v*)&hi[i] = h4;
        *(ushort4v*)&lo[i] = l4;
    }
}

// ---- bf16x3 MFMA GEMM (prep only): C = A @ Wt^T + bias, K=512 -------------------------
__global__ __launch_bounds__(64) void gemm_bf16x3(
    const unsigned short* __restrict__ Ahi, const unsigned short* __restrict__ Alo,
    const unsigned short* __restrict__ Bhi, const unsigned short* __restrict__ Blo,
    const float* __restrict__ bias, float* __restrict__ C, int Ncols)
{
    const int K = H2;
    int l = threadIdx.x;
    int n0 = blockIdx.x * 64, m0 = blockIdx.y * 64;
    int lr = l & 15, lg = l >> 4;
    f32x4 acc[4][4] = {};
    size_t aoff = (size_t)(m0 + lr) * K + lg * 8;
    size_t boff = (size_t)(n0 + lr) * K + lg * 8;
    #pragma unroll 2
    for (int ks = 0; ks < 16; ks++) {
        bf16x8 ah[4], al[4], bh[4], bl[4];
        #pragma unroll
        for (int mt = 0; mt < 4; mt++) {
            size_t o = aoff + (size_t)mt * 16 * K + ks * 32;
            ah[mt] = *(const bf16x8*)(Ahi + o);
            al[mt] = *(const bf16x8*)(Alo + o);
        }
        #pragma unroll
        for (int nt = 0; nt < 4; nt++) {
            size_t o = boff + (size_t)nt * 16 * K + ks * 32;
            bh[nt] = *(const bf16x8*)(Bhi + o);
            bl[nt] = *(const bf16x8*)(Blo + o);
        }
        #pragma unroll
        for (int mt = 0; mt < 4; mt++)
            #pragma unroll
            for (int nt = 0; nt < 4; nt++) {
                acc[mt][nt] = __builtin_amdgcn_mfma_f32_16x16x32_bf16(ah[mt], bh[nt], acc[mt][nt], 0, 0, 0);
                acc[mt][nt] = __builtin_amdgcn_mfma_f32_16x16x32_bf16(ah[mt], bl[nt], acc[mt][nt], 0, 0, 0);
                acc[mt][nt] = __builtin_amdgcn_mfma_f32_16x16x32_bf16(al[mt], bh[nt], acc[mt][nt], 0, 0, 0);
            }
    }
    #pragma unroll
    for (int mt = 0; mt < 4; mt++)
        #pragma unroll
        for (int r = 0; r < 4; r++) {
            int m = m0 + mt * 16 + lg * 4 + r;
            #pragma unroll
            for (int nt = 0; nt < 4; nt++) {
                int n = n0 + nt * 16 + lr;
                C[(size_t)m * Ncols + n] = acc[mt][nt][r] + bias[n];
            }
        }
}

// ---- per-step vocab projection: 4 waves/block, partials (NO atomics) ------------------
// grid = 500; block covers 64 vocab cols; wave w covers cols [n0+16w, n0+16w+16)
__global__ __launch_bounds__(256) void proj_mfma(
    const unsigned short* __restrict__ Ahi, const unsigned short* __restrict__ Alo,  // [64][512]
    const unsigned short* __restrict__ Bhi, const unsigned short* __restrict__ Blo,  // [V][512]
    const float* __restrict__ Fb, float* __restrict__ ys,
    unsigned long long* __restrict__ part, int t)
{
    const int K = H2;
    int tid = threadIdx.x;
    int wid = tid >> 6, l = tid & 63;
    int lr = l & 15, lg = l >> 4;
    int n0 = blockIdx.x * 64 + wid * 16;
    f32x4 acc[4] = {};
    size_t aoff = (size_t)lr * K + lg * 8;
    size_t boff = (size_t)(n0 + lr) * K + lg * 8;
    #pragma unroll 2
    for (int ks = 0; ks < 16; ks++) {
        bf16x8 ah[4], al[4], bh, bl;
        #pragma unroll
        for (int mt = 0; mt < 4; mt++) {
            size_t o = aoff + (size_t)mt * 16 * K + ks * 32;
            ah[mt] = *(const bf16x8*)(Ahi + o);
            al[mt] = *(const bf16x8*)(Alo + o);
        }
        {
            size_t o = boff + ks * 32;
            bh = *(const bf16x8*)(Bhi + o);
            bl = *(const bf16x8*)(Blo + o);
        }
        #pragma unroll
        for (int mt = 0; mt < 4; mt++) {
            acc[mt] = __builtin_amdgcn_mfma_f32_16x16x32_bf16(ah[mt], bh, acc[mt], 0, 0, 0);
            acc[mt] = __builtin_amdgcn_mfma_f32_16x16x32_bf16(ah[mt], bl, acc[mt], 0, 0, 0);
            acc[mt] = __builtin_amdgcn_mfma_f32_16x16x32_bf16(al[mt], bh, acc[mt], 0, 0, 0);
        }
    }
    #pragma unroll
    for (int mt = 0; mt < 4; mt++)
        #pragma unroll
        for (int r = 0; r < 4; r++) {
            int m = mt * 16 + lg * 4 + r;   // batch row
            int n = n0 + lr;
            float y = acc[mt][r] + Fb[n];
            ys[(size_t)m * (T * (size_t)VOCAB) + (size_t)t * VOCAB + n] = y;
            unsigned u = __float_as_uint(y);
            u = (u & 0x80000000u) ? ~u : (u | 0x80000000u);
            unsigned long long best = ((unsigned long long)u << 32) | (unsigned)(~n);
            #pragma unroll
            for (int o = 1; o < 16; o <<= 1) {
                unsigned long long other = __shfl_xor(best, o);
                if (other > best) best = other;
            }
            if (lr == 0) part[(size_t)m * PW + blockIdx.x * 4 + wid] = best;
        }
}

// ---- per-step attention: argmax-reduce + emb + attention ------------------------------
__global__ __launch_bounds__(512) void attn_step(
    const float* __restrict__ enc, const float* __restrict__ encp,
    const float* __restrict__ Uw2T, const float* __restrict__ Ub,
    const float* __restrict__ Vw, const float* __restrict__ Vb,
    const float* __restrict__ hsrc,
    const unsigned long long* __restrict__ part,
    const float* __restrict__ emb,
    float* __restrict__ xin, int is_t0)
{
    __shared__ float hf[H];
    __shared__ float qp[H2];
    __shared__ float sc[S];
    __shared__ unsigned long long wbest[8];
    __shared__ int sidx;
    __shared__ float rmax, rsum;
    int b = blockIdx.x, tid = threadIdx.x;

    // ---- stage A: reduce 2000 partial argmax keys -> token index ----
    if (is_t0) {
        if (tid == 0) sidx = 0;
    } else {
        unsigned long long best = 0ULL;
        const unsigned long long* pr = part + (size_t)b * PW;
        for (int i = tid; i < 2000; i += 512) {
            unsigned long long v = pr[i];
            if (v > best) best = v;
        }
        #pragma unroll
        for (int o = 32; o; o >>= 1) {
            unsigned long long v = __shfl_xor(best, o);
            if (v > best) best = v;
        }
        if ((tid & 63) == 0) wbest[tid >> 6] = best;
        __syncthreads();
        if (tid == 0) {
            unsigned long long bb = wbest[0];
            #pragma unroll
            for (int i = 1; i < 8; i++) if (wbest[i] > bb) bb = wbest[i];
            sidx = (int)(~(unsigned)bb);
        }
    }

    if (tid < H) hf[tid] = hsrc[b * H + tid];
    __syncthreads();

    // emb feedback -> xin[b][512:768]
    if (tid < H) {
        xin[b * H3 + H2 + tid] = emb[(size_t)sidx * H + tid];
    }

    // qp[j] = Ub[j] + sum_k hf[k] * Uw2T[k][j]; 4 accumulators, batched loads
    {
        float s0 = Ub[tid], s1 = 0.f, s2 = 0.f, s3 = 0.f;
        #pragma unroll 8
        for (int k = 0; k < H; k += 4) {
            s0 += hf[k]     * Uw2T[(k)     * H2 + tid];
            s1 += hf[k + 1] * Uw2T[(k + 1) * H2 + tid];
            s2 += hf[k + 2] * Uw2T[(k + 2) * H2 + tid];
            s3 += hf[k + 3] * Uw2T[(k + 3) * H2 + tid];
        }
        qp[tid] = (s0 + s1) + (s2 + s3);
    }
    __syncthreads();

    // scores
    {
        int si = tid >> 2, p = tid & 3;
        const float* ep = encp + ((size_t)(b * S + si)) * H2;
        float a = 0.f;
        for (int m = 0; m < 32; m++) {
            int q = (m * 4 + p) * 4;
            float4 e4 = *(const float4*)(ep + q);
            float4 v4 = *(const float4*)(Vw + q);
            float4 q4 = *(const float4*)(qp + q);
            a += v4.x * tanhf(q4.x + e4.x);
            a += v4.y * tanhf(q4.y + e4.y);
            a += v4.z * tanhf(q4.z + e4.z);
            a += v4.w * tanhf(q4.w + e4.w);
        }
        a += __shfl_xor(a, 1);
        a += __shfl_xor(a, 2);
        if (p == 0) sc[si] = a + Vb[0];
    }
    __syncthreads();

    // softmax over S=128
    if (tid < 64) {
        float m = fmaxf(sc[tid], sc[tid + 64]);
        #pragma unroll
        for (int o = 32; o; o >>= 1) m = fmaxf(m, __shfl_xor(m, o));
        if (tid == 0) rmax = m;
    }
    __syncthreads();
    if (tid < S) sc[tid] = expf(sc[tid] - rmax);
    __syncthreads();
    if (tid < 64) {
        float s = sc[tid] + sc[tid + 64];
        #pragma unroll
        for (int o = 32; o; o >>= 1) s += __shfl_xor(s, o);
        if (tid == 0) rsum = s;
    }
    __syncthreads();
    if (tid < S) sc[tid] = sc[tid] / rsum;
    __syncthreads();

    // ctx: 2 accumulators, batched loads
    {
        float a0 = 0.f, a1 = 0.f;
        const float* eb = enc + (size_t)b * S * H2 + tid;
        #pragma unroll 8
        for (int s2 = 0; s2 < S; s2 += 2) {
            a0 += sc[s2]     * eb[(size_t)(s2)     * H2];
            a1 += sc[s2 + 1] * eb[(size_t)(s2 + 1) * H2];
        }
        xin[b * H3 + tid] = a0 + a1;
    }
}

// ---- per-step LSTM (both dirs fused) --------------------------------------------------
__global__ __launch_bounds__(256) void lstm_step(
    const float* __restrict__ xin,
    const float* __restrict__ hsrc, const float* __restrict__ csrc,
    const float* __restrict__ Wih_f, const float* __restrict__ Whh_f, const float* __restrict__ bf,
    const float* __restrict__ Wih_b, const float* __restrict__ Whh_b, const float* __restrict__ bb,
    float* __restrict__ hdst, float* __restrict__ cdst,
    unsigned short* __restrict__ outb_hi, unsigned short* __restrict__ outb_lo,
    int is_last, float* __restrict__ out_tail)
{
    __shared__ float xs[64][65];   // transposed: xs[k][row]
    __shared__ float Ws[16][68];
    int blk = blockIdx.x;
    int dir = blk >> 6;
    int jg = blk & 63;
    int tid = threadIdx.x;
    int b = tid & 63, j4 = tid >> 6;
    const float* Wih = dir ? Wih_b : Wih_f;
    const float* Whh = dir ? Whh_b : Whh_f;
    const float* bias = dir ? bb : bf;
    int n = jg * 4 + j4;
    float acc[4];
    #pragma unroll
    for (int g = 0; g < 4; g++) acc[g] = bias[g * 256 + n];

    for (int k0 = 0; k0 < H3; k0 += 64) {
        #pragma unroll
        for (int i = 0; i < 4; i++) {
            int r = (tid >> 4) + i * 16;
            int c = tid & 15;
            float4 v = *(const float4*)&xin[r * H3 + k0 + c * 4];
            xs[c * 4 + 0][r] = v.x; xs[c * 4 + 1][r] = v.y;
            xs[c * 4 + 2][r] = v.z; xs[c * 4 + 3][r] = v.w;
        }
        {
            int r = tid >> 4, c = tid & 15;
            int grow = (r & 3) * 256 + jg * 4 + (r >> 2);
            *(float4*)&Ws[r][c * 4] = *(const float4*)&Wih[(size_t)grow * H3 + k0 + c * 4];
        }
        __syncthreads();
        #pragma unroll
        for (int k = 0; k < 64; k += 4) {
            float x0 = xs[k][b], x1 = xs[k + 1][b], x2 = xs[k + 2][b], x3 = xs[k + 3][b];
            #pragma unroll
            for (int g = 0; g < 4; g++) {
                float4 w4 = *(float4*)&Ws[j4 * 4 + g][k];
                acc[g] += x0 * w4.x + x1 * w4.y + x2 * w4.z + x3 * w4.w;
            }
        }
        __syncthreads();
    }
    for (int k0 = 0; k0 < H; k0 += 64) {
        #pragma unroll
        for (int i = 0; i < 4; i++) {
            int r = (tid >> 4) + i * 16;
            int c = tid & 15;
            float4 v = *(const float4*)&hsrc[dir * B * H + r * H + k0 + c * 4];
            xs[c * 4 + 0][r] = v.x; xs[c * 4 + 1][r] = v.y;
            xs[c * 4 + 2][r] = v.z; xs[c * 4 + 3][r] = v.w;
        }
        {
            int r = tid >> 4, c = tid & 15;
            int grow = (r & 3) * 256 + jg * 4 + (r >> 2);
            *(float4*)&Ws[r][c * 4] = *(const float4*)&Whh[(size_t)grow * H + k0 + c * 4];
        }
        __syncthreads();
        #pragma unroll
        for (int k = 0; k < 64; k += 4) {
            float x0 = xs[k][b], x1 = xs[k + 1][b], x2 = xs[k + 2][b], x3 = xs[k + 3][b];
            #pragma unroll
            for (int g = 0; g < 4; g++) {
                float4 w4 = *(float4*)&Ws[j4 * 4 + g][k];
                acc[g] += x0 * w4.x + x1 * w4.y + x2 * w4.z + x3 * w4.w;
            }
        }
        __syncthreads();
    }

    float iv = 1.f / (1.f + expf(-acc[0]));
    float fv = 1.f / (1.f + expf(-acc[1]));
    float gv = tanhf(acc[2]);
    float ov = 1.f / (1.f + expf(-acc[3]));
    float cold = csrc[dir * B * H + b * H + n];
    float c2 = fv * cold + iv * gv;
    float h2 = ov * tanhf(c2);
    hdst[dir * B * H + b * H + n] = h2;
    cdst[dir * B * H + b * H + n] = c2;
    unsigned short hh, hl;
    split2(h2, hh, hl);
    outb_hi[b * H2 + dir * H + n] = hh;
    outb_lo[b * H2 + dir * H + n] = hl;
    if (is_last) {
        out_tail[dir * B * H + b * H + n] = h2;
        out_tail[2 * B * H + dir * B * H + b * H + n] = c2;
    }
}

// ---- host launch ----------------------------------------------------------------------
static inline size_t align256(size_t x) { return (x + 255) & ~(size_t)255; }

extern "C" void kernel_launch(void* const* d_in, const int* in_sizes, int n_in,
                              void* d_out, int out_size, void* d_ws, size_t ws_size,
                              hipStream_t stream) {
    const float* enc   = (const float*)d_in[0];
    const float* h0    = (const float*)d_in[1];
    const float* c0    = (const float*)d_in[2];
    const float* Uw    = (const float*)d_in[3];
    const float* Ub    = (const float*)d_in[4];
    const float* Ww    = (const float*)d_in[5];
    const float* Wb    = (const float*)d_in[6];
    const float* Vw    = (const float*)d_in[7];
    const float* Vb    = (const float*)d_in[8];
    const float* Wih_f = (const float*)d_in[9];
    const float* Whh_f = (const float*)d_in[10];
    const float* b_f   = (const float*)d_in[11];
    const float* Wih_b = (const float*)d_in[12];
    const float* Whh_b = (const float*)d_in[13];
    const float* b_b   = (const float*)d_in[14];
    const float* Fw    = (const float*)d_in[15];
    const float* Fb    = (const float*)d_in[16];
    const float* emb   = (const float*)d_in[17];
    float* out = (float*)d_out;

    char* p = (char*)d_ws;
    size_t off = 0;
    #define ALLOC(name, bytes) char* name##_p = p + off; off = align256(off + (bytes))
    ALLOC(encp, (size_t)B * S * H2 * 4);
    ALLOC(uw2t, (size_t)H * H2 * 4);
    ALLOC(xin,  (size_t)B * H3 * 4);
    ALLOC(hA,   (size_t)2 * B * H * 4);
    ALLOC(hB,   (size_t)2 * B * H * 4);
    ALLOC(cA,   (size_t)2 * B * H * 4);
    ALLOC(cB,   (size_t)2 * B * H * 4);
    ALLOC(obh,  (size_t)B * H2 * 2);
    ALLOC(obl,  (size_t)B * H2 * 2);
    ALLOC(fwh,  (size_t)VOCAB * H2 * 2);
    ALLOC(fwl,  (size_t)VOCAB * H2 * 2);
    ALLOC(ench, (size_t)B * S * H2 * 2);
    ALLOC(encl, (size_t)B * S * H2 * 2);
    ALLOC(wwh,  (size_t)H2 * H2 * 2);
    ALLOC(wwl,  (size_t)H2 * H2 * 2);
    ALLOC(part, (size_t)B * PW * 8);
    #undef ALLOC

    float* encp_f = (float*)encp_p;
    float* Uw2T   = (float*)uw2t_p;
    float* xin_f  = (float*)xin_p;
    float* hA_f = (float*)hA_p; float* hB_f = (float*)hB_p;
    float* cA_f = (float*)cA_p; float* cB_f = (float*)cB_p;
    unsigned short* obh_u = (unsigned short*)obh_p;
    unsigned short* obl_u = (unsigned short*)obl_p;
    unsigned short* fwh_u = (unsigned short*)fwh_p;
    unsigned short* fwl_u = (unsigned short*)fwl_p;
    unsigned short* ench_u = (unsigned short*)ench_p;
    unsigned short* encl_u = (unsigned short*)encl_p;
    unsigned short* wwh_u = (unsigned short*)wwh_p;
    unsigned short* wwl_u = (unsigned short*)wwl_p;
    unsigned long long* part_u = (unsigned long long*)part_p;

    prep_uw2t<<<(H * H2 + 255) / 256, 256, 0, stream>>>(Uw, Uw2T);
    split_bf16<<<2048, 256, 0, stream>>>(Fw, fwh_u, fwl_u, VOCAB * H2);
    split_bf16<<<1024, 256, 0, stream>>>(enc, ench_u, encl_u, B * S * H2);
    split_bf16<<<256, 256, 0, stream>>>(Ww, wwh_u, wwl_u, H2 * H2);
    gemm_bf16x3<<<dim3(8, 128), 64, 0, stream>>>(ench_u, encl_u, wwh_u, wwl_u, Wb, encp_f, H2);

    for (int t = 0; t < T; t++) {
        const float* hsrc = (t == 0) ? h0 : ((t & 1) ? hA_f : hB_f);
        const float* csrc = (t == 0) ? c0 : ((t & 1) ? cA_f : cB_f);
        float* hdst = (t & 1) ? hB_f : hA_f;
        float* cdst = (t & 1) ? cB_f : cA_f;

        attn_step<<<B, 512, 0, stream>>>(enc, encp_f, Uw2T, Ub, Vw, Vb,
                                         hsrc, part_u, emb, xin_f, (t == 0) ? 1 : 0);
        lstm_step<<<128, 256, 0, stream>>>(xin_f, hsrc, csrc,
                                           Wih_f, Whh_f, b_f, Wih_b, Whh_b, b_b,
                                           hdst, cdst, obh_u, obl_u,
                                           (t == T - 1) ? 1 : 0,
                                           out + (size_t)B * T * VOCAB);
        proj_mfma<<<VOCAB / 64, 256, 0, stream>>>(obh_u, obl_u, fwh_u, fwl_u,
                                                  Fb, out, part_u, t);
    }
}